// Round 1
// baseline (377.702 us; speedup 1.0000x reference)
//
#include <hip/hip_runtime.h>
#include <math.h>

#define N_NODES 50000
#define N_EDGES 640000
#define DIM     128
#define NGRAPH  64
#define DOUT    32
#define E_TOT   (N_EDGES + N_NODES)
#define POOL_CHUNK 32

// ---- degree init (self-loop => deg starts at 1) + zero pooled ----
__global__ __launch_bounds__(256) void k_init(int* __restrict__ deg, float* __restrict__ pooled) {
    int i = blockIdx.x * 256 + threadIdx.x;
    if (i < N_NODES) deg[i] = 1;
    if (i < NGRAPH * DIM) pooled[i] = 0.f;
}

__global__ __launch_bounds__(256) void k_count_deg(const int* __restrict__ dst, int* __restrict__ deg) {
    int e = blockIdx.x * 256 + threadIdx.x;
    if (e < N_EDGES) atomicAdd(&deg[dst[e]], 1);
}

// ---- exclusive scan of deg -> row_start (3 kernels) ----
__global__ __launch_bounds__(512) void k_scan_block(const int* __restrict__ deg,
                                                    int* __restrict__ row_start,
                                                    int* __restrict__ bsum) {
    __shared__ int sd[512];
    int t = threadIdx.x;
    int i = blockIdx.x * 512 + t;
    int v = (i < N_NODES) ? deg[i] : 0;
    int sum = v;
    sd[t] = v; __syncthreads();
    for (int off = 1; off < 512; off <<= 1) {
        int o = (t >= off) ? sd[t - off] : 0;
        __syncthreads();
        sum += o; sd[t] = sum;
        __syncthreads();
    }
    if (i < N_NODES) row_start[i] = sum - v;       // exclusive within block
    if (t == 511) bsum[blockIdx.x] = sum;          // block total
}

__global__ __launch_bounds__(128) void k_scan_bsum(const int* __restrict__ bsum, int* __restrict__ boff) {
    __shared__ int sd[128];
    int t = threadIdx.x;
    int v = (t < 98) ? bsum[t] : 0;
    int sum = v;
    sd[t] = v; __syncthreads();
    for (int off = 1; off < 128; off <<= 1) {
        int o = (t >= off) ? sd[t - off] : 0;
        __syncthreads();
        sum += o; sd[t] = sum;
        __syncthreads();
    }
    if (t < 98) boff[t] = sum - v;                 // exclusive block offsets
}

__global__ __launch_bounds__(256) void k_finalize(const int* __restrict__ deg,
                                                  const int* __restrict__ boff,
                                                  int* __restrict__ row_start,
                                                  int* __restrict__ cursor,
                                                  float* __restrict__ dinv) {
    int i = blockIdx.x * 256 + threadIdx.x;
    if (i < N_NODES) {
        int r = row_start[i] + boff[i >> 9];
        row_start[i] = r;
        cursor[i]    = r;
        dinv[i]      = rsqrtf((float)deg[i]);
    } else if (i == N_NODES) {
        row_start[N_NODES] = E_TOT;
    }
}

// ---- CSR fill: real edges + self-loops ----
__global__ __launch_bounds__(256) void k_fill(const int* __restrict__ src, const int* __restrict__ dst,
                                              const float* __restrict__ dinv, int* __restrict__ cursor,
                                              int* __restrict__ csr_src, float* __restrict__ csr_norm) {
    int e = blockIdx.x * 256 + threadIdx.x;
    if (e < N_EDGES) {
        int s = src[e], d = dst[e];
        int pos = atomicAdd(&cursor[d], 1);
        csr_src[pos]  = s;
        csr_norm[pos] = dinv[s] * dinv[d];
    } else if (e < E_TOT) {
        int i = e - N_EDGES;
        int pos = atomicAdd(&cursor[i], 1);
        csr_src[pos]  = i;
        float di = dinv[i];
        csr_norm[pos] = di * di;
    }
}

// ---- fp32 GEMM: Y[M,128] = X[M,128] @ W[128,128]  (no bias; bias added post-agg) ----
// 256 threads, 64-row x 128-col tile, 8x4 outputs/thread, X tile in LDS, W from L1/L2
__global__ __launch_bounds__(256) void k_gemm(const float* __restrict__ X,
                                              const float* __restrict__ W,
                                              float* __restrict__ Y) {
    __shared__ float xs[64][DIM];
    int tid  = threadIdx.x;
    int row0 = blockIdx.x * 64;
#pragma unroll
    for (int i = 0; i < 8; ++i) {
        int idx = tid + 256 * i;          // 0..2047 float4 slots
        int r = idx >> 5, c4 = idx & 31;
        int gr = row0 + r;
        float4 v = make_float4(0.f, 0.f, 0.f, 0.f);
        if (gr < N_NODES) v = ((const float4*)(X + (size_t)gr * DIM))[c4];
        ((float4*)(&xs[r][0]))[c4] = v;
    }
    __syncthreads();
    int tx = tid & 31;     // col group: cols 4*tx..4*tx+3
    int ty = tid >> 5;     // row group: rows 8*ty..8*ty+7
    float acc[8][4] = {};
    const float4* Wp = (const float4*)W + tx;     // row k at Wp[k*32]
#pragma unroll 4
    for (int k = 0; k < DIM; ++k) {
        float4 w = Wp[k * 32];
#pragma unroll
        for (int i = 0; i < 8; ++i) {
            float xv = xs[ty * 8 + i][k];         // wave-broadcast LDS read
            acc[i][0] = fmaf(xv, w.x, acc[i][0]);
            acc[i][1] = fmaf(xv, w.y, acc[i][1]);
            acc[i][2] = fmaf(xv, w.z, acc[i][2]);
            acc[i][3] = fmaf(xv, w.w, acc[i][3]);
        }
    }
#pragma unroll
    for (int i = 0; i < 8; ++i) {
        int gr = row0 + ty * 8 + i;
        if (gr < N_NODES)
            ((float4*)(Y + (size_t)gr * DIM))[tx] =
                make_float4(acc[i][0], acc[i][1], acc[i][2], acc[i][3]);
    }
}

// ---- gather-aggregate: Out[n] = relu(bias + sum_e norm_e * H[src_e]) ; one wave per node ----
__global__ __launch_bounds__(256) void k_agg(const float* __restrict__ H,
                                             const int* __restrict__ csr_src,
                                             const float* __restrict__ csr_norm,
                                             const int* __restrict__ row_start,
                                             const float* __restrict__ bias,
                                             float* __restrict__ Out) {
    int node = blockIdx.x * 4 + (threadIdx.x >> 6);
    int lane = threadIdx.x & 63;
    if (node >= N_NODES) return;
    int e0 = row_start[node], e1 = row_start[node + 1];
    float ax = 0.f, ay = 0.f;
    for (int e = e0; e < e1; ++e) {
        int   s = csr_src[e];
        float w = csr_norm[e];
        float2 v = *((const float2*)(H + (size_t)s * DIM + lane * 2));
        ax = fmaf(w, v.x, ax);
        ay = fmaf(w, v.y, ay);
    }
    float bx = bias[lane * 2], by = bias[lane * 2 + 1];
    float2 o;
    o.x = fmaxf(ax + bx, 0.f);
    o.y = fmaxf(ay + by, 0.f);
    *((float2*)(Out + (size_t)node * DIM + lane * 2)) = o;
}

// ---- global add pool over sorted batch: register run-length + atomic flush ----
__global__ __launch_bounds__(128) void k_pool(const float* __restrict__ H,
                                              const int* __restrict__ batch,
                                              float* __restrict__ pooled) {
    int dim   = threadIdx.x;
    int start = blockIdx.x * POOL_CHUNK;
    if (start >= N_NODES) return;
    int end = min(start + POOL_CHUNK, N_NODES);
    float acc = 0.f;
    int cb = batch[start];
    for (int i = start; i < end; ++i) {
        int b = batch[i];
        if (b != cb) {
            atomicAdd(&pooled[cb * DIM + dim], acc);
            acc = 0.f; cb = b;
        }
        acc += H[(size_t)i * DIM + dim];
    }
    atomicAdd(&pooled[cb * DIM + dim], acc);
}

// ---- head: logits = pooled @ Wh + bh ; log_softmax per graph ----
__global__ __launch_bounds__(64) void k_head(const float* __restrict__ pooled,
                                             const float* __restrict__ Wh,
                                             const float* __restrict__ bh,
                                             float* __restrict__ out) {
    int g = blockIdx.x;
    int lane = threadIdx.x;
    int c = lane & 31;                 // lanes 32..63 duplicate work; only <32 write
    const float* p = pooled + g * DIM;
    float lg = bh[c];
#pragma unroll 8
    for (int k = 0; k < DIM; ++k) lg = fmaf(p[k], Wh[k * DOUT + c], lg);
    float m = lg;
    for (int off = 16; off >= 1; off >>= 1) m = fmaxf(m, __shfl_xor(m, off, 32));
    float ex = expf(lg - m);
    float s = ex;
    for (int off = 16; off >= 1; off >>= 1) s += __shfl_xor(s, off, 32);
    if (lane < 32) out[g * DOUT + c] = lg - m - logf(s);
}

extern "C" void kernel_launch(void* const* d_in, const int* in_sizes, int n_in,
                              void* d_out, int out_size, void* d_ws, size_t ws_size,
                              hipStream_t stream) {
    const float* x     = (const float*)d_in[0];
    const int*   ei    = (const int*)d_in[1];
    const int*   batch = (const int*)d_in[2];
    const float* W1    = (const float*)d_in[3];
    const float* b1    = (const float*)d_in[4];
    const float* W2    = (const float*)d_in[5];
    const float* b2    = (const float*)d_in[6];
    const float* Wh    = (const float*)d_in[7];
    const float* bh    = (const float*)d_in[8];
    float* out = (float*)d_out;
    const int* src = ei;
    const int* dst = ei + N_EDGES;

    char* ws = (char*)d_ws;
    size_t off = 0;
    auto alloc = [&](size_t bytes) {
        void* p = ws + off;
        off += (bytes + 255) & ~(size_t)255;
        return p;
    };
    float* bufA      = (float*)alloc((size_t)N_NODES * DIM * 4);   // 25.6 MB
    float* bufB      = (float*)alloc((size_t)N_NODES * DIM * 4);   // 25.6 MB
    int*   deg       = (int*)  alloc((size_t)N_NODES * 4);
    float* dinv      = (float*)alloc((size_t)N_NODES * 4);
    int*   row_start = (int*)  alloc((size_t)(N_NODES + 1) * 4);
    int*   cursor    = (int*)  alloc((size_t)N_NODES * 4);
    int*   csr_src   = (int*)  alloc((size_t)E_TOT * 4);
    float* csr_norm  = (float*)alloc((size_t)E_TOT * 4);
    float* pooled    = (float*)alloc((size_t)NGRAPH * DIM * 4);
    int*   bsum      = (int*)  alloc(128 * 4);
    int*   boff      = (int*)  alloc(128 * 4);
    (void)ws_size; (void)in_sizes; (void)n_in; (void)out_size;

    k_init      <<<(N_NODES + 255) / 256, 256, 0, stream>>>(deg, pooled);
    k_count_deg <<<(N_EDGES + 255) / 256, 256, 0, stream>>>(dst, deg);
    k_scan_block<<<98, 512, 0, stream>>>(deg, row_start, bsum);
    k_scan_bsum <<<1, 128, 0, stream>>>(bsum, boff);
    k_finalize  <<<(N_NODES + 256) / 256, 256, 0, stream>>>(deg, boff, row_start, cursor, dinv);
    k_fill      <<<(E_TOT + 255) / 256, 256, 0, stream>>>(src, dst, dinv, cursor, csr_src, csr_norm);

    k_gemm<<<(N_NODES + 63) / 64, 256, 0, stream>>>(x, W1, bufA);
    k_agg <<<(N_NODES + 3) / 4, 256, 0, stream>>>(bufA, csr_src, csr_norm, row_start, b1, bufB);
    k_gemm<<<(N_NODES + 63) / 64, 256, 0, stream>>>(bufB, W2, bufA);
    k_agg <<<(N_NODES + 3) / 4, 256, 0, stream>>>(bufA, csr_src, csr_norm, row_start, b2, bufB);

    k_pool<<<(N_NODES + POOL_CHUNK - 1) / POOL_CHUNK, 128, 0, stream>>>(bufB, batch, pooled);
    k_head<<<NGRAPH, 64, 0, stream>>>(pooled, Wh, bh, out);
}